// Round 4
// baseline (208.235 us; speedup 1.0000x reference)
//
#include <hip/hip_runtime.h>
#include <stdint.h>
#include <stddef.h>

// Problem constants (B=2, S=2048, D=2048, H=16, KVH=4, HD=128)
#define S_LEN  2048
#define NH     16
#define NKVH   4
#define HD_    128
#define DMODEL 2048
#define NQKV   3072      // H*HD + 2*KVH*HD
#define MROWS  4096      // B*S

typedef __attribute__((ext_vector_type(8)))  __bf16 bf16x8;
typedef __attribute__((ext_vector_type(4)))  __bf16 bf16x4;
typedef __attribute__((ext_vector_type(4)))  float  f32x4;
typedef __attribute__((ext_vector_type(16))) float  f32x16;

#define MFMA16(a, b, c) __builtin_amdgcn_mfma_f32_16x16x32_bf16((a), (b), (c), 0, 0, 0)
#define MFMA32(a, b, c) __builtin_amdgcn_mfma_f32_32x32x16_bf16((a), (b), (c), 0, 0, 0)

__device__ __forceinline__ void gload16(const void* g, void* l) {
  __builtin_amdgcn_global_load_lds((const __attribute__((address_space(1))) void*)g,
                                   (__attribute__((address_space(3))) void*)l,
                                   16, 0, 0);
}

// packed f32x2 -> bf16x2 (no builtin on gfx950; guide T12)
__device__ __forceinline__ uint32_t cvtpk(float lo, float hi) {
  uint32_t d;
  asm("v_cvt_pk_bf16_f32 %0, %1, %2" : "=v"(d) : "v"(lo), "v"(hi));
  return d;
}
// v_permlane32_swap_b32: a[32:63] <-> b[0:31].  s_nop guards the
// VALU-write -> permlane cross-lane-read hazard across asm blocks.
// a and b MUST be distinct SSA values (equal values coalesce to one VGPR
// and the swap self-cancels — round-2 bug).
__device__ __forceinline__ void pswap(uint32_t& a, uint32_t& b) {
  asm("s_nop 1\n\tv_permlane32_swap_b32 %0, %1" : "+v"(a), "+v"(b));
}

// ---------------------------------------------------------------------------
// 1) prep: blocks [0,8192): x f32 -> xb bf16 (float4 each thread)
//          blocks [8192,10752): 64x64 LDS-tiled transpose of wq/wk/wv/wo
//          into bf16 [N][K] layouts.
// ---------------------------------------------------------------------------
__global__ void prep_kernel(const float* __restrict__ x, __bf16* __restrict__ xb,
                            const float* __restrict__ wq, const float* __restrict__ wk,
                            const float* __restrict__ wv, const float* __restrict__ wo,
                            __bf16* __restrict__ wqkvT, __bf16* __restrict__ woT) {
  __shared__ float tile[64][65];
  const int bid = blockIdx.x;
  const int tid = threadIdx.x;
  if (bid < 8192) {
    size_t i = (size_t)bid * 256 + tid;
    const float4* xv = (const float4*)x;
    float4 v = xv[i];
    bf16x4 o;
    o[0] = (__bf16)v.x; o[1] = (__bf16)v.y; o[2] = (__bf16)v.z; o[3] = (__bf16)v.w;
    *(bf16x4*)(xb + i * 4) = o;
    return;
  }
  int b2 = bid - 8192;
  const float* W; __bf16* WT; int ldw, kx, ny;
  if (b2 < 1024)      { W = wq; WT = wqkvT;                        ldw = 2048; kx = b2 & 31; ny = b2 >> 5; }
  else if (b2 < 1280) { int t = b2 - 1024; W = wk; WT = wqkvT + (size_t)2048 * 2048; ldw = 512; kx = t & 31; ny = t >> 5; }
  else if (b2 < 1536) { int t = b2 - 1280; W = wv; WT = wqkvT + (size_t)2560 * 2048; ldw = 512; kx = t & 31; ny = t >> 5; }
  else                { int t = b2 - 1536; W = wo; WT = woT;       ldw = 2048; kx = t & 31; ny = t >> 5; }
  const int k0 = kx * 64, n0 = ny * 64;
#pragma unroll
  for (int r = 0; r < 16; ++r) {
    int idx = r * 256 + tid;
    int kr = idx >> 6, nc = idx & 63;
    tile[kr][nc] = W[(size_t)(k0 + kr) * ldw + n0 + nc];
  }
  __syncthreads();
#pragma unroll
  for (int r = 0; r < 16; ++r) {
    int idx = r * 256 + tid;
    int nr = idx >> 6, kc = idx & 63;
    WT[(size_t)(n0 + nr) * 2048 + k0 + kc] = (__bf16)tile[kc][nr];
  }
}

// ---------------------------------------------------------------------------
// 2/5) bf16 GEMM: C[M][N] = A[M][K] * Bt[N][K]^T.  128x128 tile, BK=64,
// 4 waves (2x2), 4x4 16x16x32 frags/wave.  global_load_lds(16B) staging with
// XOR swizzle applied on the *source* address (LDS dest linear) and on reads.
// DO_ROPE: fused RoPE epilogue on Q cols [0,2048) (also scaled by
// log2(e)/sqrt(HD), for the exp2-domain softmax) and K cols [2048,2560).
// Pair (2j,2j+1) lives in lane^1 (C-frag col = lane&15) -> one shfl_xor.
// ---------------------------------------------------------------------------
template <int OUT_F32, int DO_ROPE>
__global__ __launch_bounds__(256, 2) void gemm_kernel(
    const __bf16* __restrict__ A, int lda,
    const __bf16* __restrict__ Bt, int ldb,
    void* __restrict__ Cout, int ldc, int Kdim,
    const float* __restrict__ fc, const float* __restrict__ fs) {
  __shared__ __attribute__((aligned(16))) __bf16 As[128 * 64];
  __shared__ __attribute__((aligned(16))) __bf16 Bs[128 * 64];
  const int tid = threadIdx.x;
  const int w = tid >> 6, l = tid & 63, lg = l >> 4, lr = l & 15;
  const int wm = w >> 1, wn = w & 1;
  const int m0 = blockIdx.y * 128, n0 = blockIdx.x * 128;

  f32x4 acc[4][4] = {};

  for (int k0 = 0; k0 < Kdim; k0 += 64) {
#pragma unroll
    for (int t = 0; t < 4; ++t) {
      int o = (t * 256 + tid) * 16;       // linear byte offset in 16KB tile
      int row = o >> 7;                   // 128B rows (64 bf16)
      int slot = (o >> 4) & 7;
      int sw = slot ^ (row & 7);          // involution: pre-swizzled source
      gload16(A + (size_t)(m0 + row) * lda + k0 + sw * 8,
              (char*)As + t * 4096 + (w << 10));
      gload16(Bt + (size_t)(n0 + row) * ldb + k0 + sw * 8,
              (char*)Bs + t * 4096 + (w << 10));
    }
    __syncthreads();
#pragma unroll
    for (int c = 0; c < 2; ++c) {
      bf16x8 af[4];
#pragma unroll
      for (int mi = 0; mi < 4; ++mi) {
        int row = wm * 64 + mi * 16 + lr;
        int slot = (c * 4 + lg) ^ (row & 7);
        af[mi] = *(const bf16x8*)((const char*)As + row * 128 + slot * 16);
      }
#pragma unroll
      for (int ni = 0; ni < 4; ++ni) {
        int rn = wn * 64 + ni * 16 + lr;
        int slot = (c * 4 + lg) ^ (rn & 7);
        bf16x8 bfr = *(const bf16x8*)((const char*)Bs + rn * 128 + slot * 16);
#pragma unroll
        for (int mi = 0; mi < 4; ++mi)
          acc[mi][ni] = MFMA16(af[mi], bfr, acc[mi][ni]);
      }
    }
    __syncthreads();
  }

  if (DO_ROPE && n0 < 2560) {
    // RoPE epilogue (Q: scale by log2e/sqrt(128); K: no scale); V never here.
    const float qs = 0.12755102871936672f;   // log2(e)/sqrt(128)
#pragma unroll
    for (int mi = 0; mi < 4; ++mi)
#pragma unroll
      for (int ni = 0; ni < 4; ++ni)
#pragma unroll
        for (int i = 0; i < 4; ++i) {
          float v = acc[mi][ni][i];
          float p = __shfl_xor(v, 1);        // partner of the (xr,xi) pair
          int cc = n0 + wn * 64 + ni * 16 + lr;
          int r  = m0 + wm * 64 + mi * 16 + lg * 4 + i;
          int s  = r & (S_LEN - 1);
          int j  = (cc & 127) >> 1;
          float c = fc[s * 64 + j], sn = fs[s * 64 + j];
          float o = (lr & 1) ? (p * sn + v * c)    // odd col: xr*sin + xi*cos
                             : (v * c - p * sn);   // even col: xr*cos - xi*sin
          if (cc < DMODEL) o *= qs;
          ((__bf16*)Cout)[(size_t)r * ldc + cc] = (__bf16)o;
        }
    return;
  }

#pragma unroll
  for (int mi = 0; mi < 4; ++mi)
#pragma unroll
    for (int ni = 0; ni < 4; ++ni)
#pragma unroll
      for (int i = 0; i < 4; ++i) {
        int r = m0 + wm * 64 + mi * 16 + lg * 4 + i;
        int cc = n0 + wn * 64 + ni * 16 + lr;
        if (OUT_F32)
          ((float*)Cout)[(size_t)r * ldc + cc] = acc[mi][ni][i];
        else
          ((__bf16*)Cout)[(size_t)r * ldc + cc] = (__bf16)acc[mi][ni][i];
      }
}

// ---------------------------------------------------------------------------
// 3) V part of qkv (cols [2560,3072)) -> VT [b][kvh][d][s] bf16 (64x64 tiles)
// ---------------------------------------------------------------------------
__global__ void vt_kernel(const __bf16* __restrict__ qkv, __bf16* __restrict__ VT) {
  __shared__ uint16_t tile[64][66];
  const int bkv = blockIdx.z;            // b*4 + kvh
  const int b = bkv >> 2, kv = bkv & 3;
  const int s0 = blockIdx.x * 64, d0 = blockIdx.y * 64;
  const int tid = threadIdx.x;
#pragma unroll
  for (int r = 0; r < 16; ++r) {
    int idx = r * 256 + tid;
    int sr = idx >> 6, dc = idx & 63;
    tile[sr][dc] = *(const uint16_t*)(qkv + (size_t)(b * S_LEN + s0 + sr) * NQKV +
                                      (DMODEL + NKVH * HD_) + kv * HD_ + d0 + dc);
  }
  __syncthreads();
#pragma unroll
  for (int r = 0; r < 16; ++r) {
    int idx = r * 256 + tid;
    int dr = idx >> 6, sc = idx & 63;
    *(uint16_t*)(VT + (size_t)(bkv * HD_ + d0 + dr) * S_LEN + s0 + sc) = tile[sc][dr];
  }
}

// ---------------------------------------------------------------------------
// 4) Flash attention — swapped-operand 32x32 MFMA, exp2-domain softmax,
// double-buffered K/V staging (T3 minimum 2-phase: issue next tile's
// global_load_lds BEFORE computing the current tile; the __syncthreads()
// vmcnt-drain then lands after ~600cy of compute instead of stalling).
// ---------------------------------------------------------------------------
__global__ __launch_bounds__(256, 2) void attn_kernel(
    const __bf16* __restrict__ qkv, const __bf16* __restrict__ VT,
    __bf16* __restrict__ out) {
  __shared__ __attribute__((aligned(16))) __bf16 Ks[2][64 * 128];
  __shared__ __attribute__((aligned(16))) __bf16 Vs[2][128 * 64];
  const int tid = threadIdx.x;
  const int w = tid >> 6, l = tid & 63;
  const int qc = l & 31, hi = l >> 5;
  const int bh = blockIdx.y;             // 0..31
  const int b = bh >> 4, h = bh & 15, kvh = h >> 2;
  const int q0 = blockIdx.x * 128 + w * 32;   // wave's first q row within S

  const __bf16* Kbase = qkv + (size_t)b * S_LEN * NQKV + DMODEL + kvh * HD_;
  const __bf16* Vbase = VT + (size_t)(b * NKVH + kvh) * (HD_ * S_LEN);

  // stage K tile [64][256B] and V^T tile [128][128B] for kv-tile kt into buf
  auto stage = [&](int kt, int bufi) {
#pragma unroll
    for (int t = 0; t < 4; ++t) {
      int o = (t * 256 + tid) * 16;
      {
        int row = o >> 8; int slot = (o >> 4) & 15; int sw = slot ^ (row & 7);
        gload16(Kbase + (size_t)(kt * 64 + row) * NQKV + sw * 8,
                (char*)Ks[bufi] + t * 4096 + (w << 10));
      }
      {
        int row = o >> 7; int slot = (o >> 4) & 7; int sw = slot ^ (row & 7);
        gload16(Vbase + (size_t)row * S_LEN + kt * 64 + sw * 8,
                (char*)Vs[bufi] + t * 4096 + (w << 10));
      }
    }
  };

  // Q fragments (B-operand): lane holds Q[q0+qc][k = c*16 + hi*8 + j]
  bf16x8 aq[8];
#pragma unroll
  for (int c = 0; c < 8; ++c)
    aq[c] = *(const bf16x8*)(qkv + (size_t)(b * S_LEN + q0 + qc) * NQKV +
                             h * HD_ + c * 16 + hi * 8);

  f32x16 o_acc[4] = {};                  // O^T: rows d = 32dt + crow(r,hi), col q
  float m = -1e30f, lsum = 0.0f;

  typedef union { uint32_t u[4]; bf16x8 v; } pfrag_t;

  stage(0, 0);
  __syncthreads();
  int buf = 0;

  for (int kt = 0; kt < S_LEN / 64; ++kt) {
    if (kt + 1 < S_LEN / 64) stage(kt + 1, buf ^ 1);   // issue-early (T14/T3)

    // ---- swapped QK^T: st[t] = S^T[kv = 32t + crow(r,hi)][q = qc] (log2-dom)
    f32x16 st[2] = {};
    __builtin_amdgcn_s_setprio(1);
#pragma unroll
    for (int t = 0; t < 2; ++t) {
#pragma unroll
      for (int c = 0; c < 8; ++c) {
        int row = t * 32 + qc;
        int slot = (c * 2 + hi) ^ (row & 7);
        bf16x8 kf = *(const bf16x8*)((const char*)Ks[buf] + row * 256 + slot * 16);
        st[t] = MFMA32(kf, aq[c], st[t]);
      }
    }
    __builtin_amdgcn_s_setprio(0);

    // ---- in-register softmax (lane owns one q row; pair lane = other half)
    float pm = st[0][0];
#pragma unroll
    for (int t = 0; t < 2; ++t)
#pragma unroll
      for (int r = 0; r < 16; ++r) pm = fmaxf(pm, st[t][r]);
    pm = fmaxf(pm, __shfl_xor(pm, 32));

    if (__any(pm - m > 11.54f)) {        // defer-max (T13), 8*log2(e)
      float mn = fmaxf(m, pm);
      float sf = exp2f(m - mn);
      lsum *= sf;
#pragma unroll
      for (int dt = 0; dt < 4; ++dt)
#pragma unroll
        for (int r = 0; r < 16; ++r) o_acc[dt][r] *= sf;
      m = mn;
    }

    float rsum = 0.0f;
#pragma unroll
    for (int t = 0; t < 2; ++t)
#pragma unroll
      for (int r = 0; r < 16; ++r) {
        st[t][r] = exp2f(st[t][r] - m);
        rsum += st[t][r];
      }
    rsum += __shfl_xor(rsum, 32);
    lsum += rsum;

    // ---- pack P -> bf16 PV fragments (cvt_pk + permlane32_swap, T12)
    pfrag_t pf[4];
#pragma unroll
    for (int t = 0; t < 2; ++t)
#pragma unroll
      for (int half = 0; half < 2; ++half) {
        int bs = half * 8;
        uint32_t x0 = cvtpk(st[t][bs + 0], st[t][bs + 1]);
        uint32_t y0 = cvtpk(st[t][bs + 4], st[t][bs + 5]);
        uint32_t x1 = cvtpk(st[t][bs + 2], st[t][bs + 3]);
        uint32_t y1 = cvtpk(st[t][bs + 6], st[t][bs + 7]);
        pswap(x0, y0);
        pswap(x1, y1);
        pf[t * 2 + half].u[0] = x0;
        pf[t * 2 + half].u[1] = x1;
        pf[t * 2 + half].u[2] = y0;
        pf[t * 2 + half].u[3] = y1;
      }

    // ---- PV transposed: O^T += mfma32(V^T_frag, P^T_frag)
    __builtin_amdgcn_s_setprio(1);
#pragma unroll
    for (int dt = 0; dt < 4; ++dt) {
#pragma unroll
      for (int ks = 0; ks < 4; ++ks) {
        int row = dt * 32 + qc;
        int slot = (ks * 2 + hi) ^ (row & 7);
        bf16x8 vf = *(const bf16x8*)((const char*)Vs[buf] + row * 128 + slot * 16);
        o_acc[dt] = MFMA32(vf, pf[ks].v, o_acc[dt]);
      }
    }
    __builtin_amdgcn_s_setprio(0);
    __syncthreads();   // drains vmcnt (next-tile loads) + barrier
    buf ^= 1;
  }

  // ---- epilogue: normalize, write bf16 attn-out [b*S][H*HD]
  float rinv = 1.0f / lsum;
  const size_t orow = (size_t)(b * S_LEN + q0 + qc) * DMODEL + h * HD_;
#pragma unroll
  for (int dt = 0; dt < 4; ++dt)
#pragma unroll
    for (int rg = 0; rg < 4; ++rg) {
      bf16x4 ov;
#pragma unroll
      for (int i = 0; i < 4; ++i)
        ov[i] = (__bf16)(o_acc[dt][rg * 4 + i] * rinv);
      int d = dt * 32 + rg * 8 + hi * 4;   // crow(rg*4+i,hi) = i + 8rg + 4hi
      *(bf16x4*)(out + orow + d) = ov;
    }
}

// ---------------------------------------------------------------------------
extern "C" void kernel_launch(void* const* d_in, const int* in_sizes, int n_in,
                              void* d_out, int out_size, void* d_ws, size_t ws_size,
                              hipStream_t stream) {
  const float* x  = (const float*)d_in[0];
  const float* fc = (const float*)d_in[1];
  const float* fs = (const float*)d_in[2];
  const float* wq = (const float*)d_in[3];
  const float* wk = (const float*)d_in[4];
  const float* wv = (const float*)d_in[5];
  const float* wo = (const float*)d_in[6];
  // d_in[7]/d_in[8] caches unused (start_pos==0, s==S), d_in[9] start_pos==0.

  char* ws = (char*)d_ws;
  __bf16* xb    = (__bf16*)(ws);                         // 16 MiB (reused as attn-out)
  __bf16* wqkvT = (__bf16*)(ws + (16u << 20));           // 12 MiB: [3072][2048]
  __bf16* woT   = (__bf16*)(ws + (28u << 20));           //  8 MiB: [2048][2048]
  __bf16* qkv   = (__bf16*)(ws + (36u << 20));           // 24 MiB: [4096][3072]
  __bf16* VT    = (__bf16*)(ws + (60u << 20));           //  4 MiB: [2][4][128][2048]

  // 1) x->bf16 + all weight transposes (one launch)
  prep_kernel<<<10752, 256, 0, stream>>>(x, xb, wq, wk, wv, wo, wqkvT, woT);
  // 2) fused QKV projection + RoPE epilogue -> qkv bf16 [4096][3072]
  {
    dim3 g(NQKV / 128, MROWS / 128);
    gemm_kernel<0, 1><<<g, 256, 0, stream>>>(xb, 2048, wqkvT, 2048, qkv, NQKV, 2048, fc, fs);
  }
  // 3) V -> V^T
  {
    dim3 g(32, 2, 8); vt_kernel<<<g, 256, 0, stream>>>(qkv, VT);
  }
  // 4) flash attention -> xb (attn-out bf16 [4096][2048])
  {
    dim3 g(S_LEN / 128, 32); attn_kernel<<<g, 256, 0, stream>>>(qkv, VT, xb);
  }
  // 5) output projection -> d_out f32
  {
    dim3 g(DMODEL / 128, MROWS / 128);
    gemm_kernel<1, 0><<<g, 256, 0, stream>>>(xb, 2048, woT, 2048, d_out, 2048, 2048, fc, fs);
  }
}

// Round 5
// 193.939 us; speedup vs baseline: 1.0737x; 1.0737x over previous
//
#include <hip/hip_runtime.h>
#include <stdint.h>
#include <stddef.h>

// Problem constants (B=2, S=2048, D=2048, H=16, KVH=4, HD=128)
#define S_LEN  2048
#define NH     16
#define NKVH   4
#define HD_    128
#define DMODEL 2048
#define NQKV   3072      // H*HD + 2*KVH*HD
#define MROWS  4096      // B*S

typedef __attribute__((ext_vector_type(8)))  __bf16 bf16x8;
typedef __attribute__((ext_vector_type(4)))  __bf16 bf16x4;
typedef __attribute__((ext_vector_type(4)))  float  f32x4;
typedef __attribute__((ext_vector_type(16))) float  f32x16;

#define MFMA16(a, b, c) __builtin_amdgcn_mfma_f32_16x16x32_bf16((a), (b), (c), 0, 0, 0)
#define MFMA32(a, b, c) __builtin_amdgcn_mfma_f32_32x32x16_bf16((a), (b), (c), 0, 0, 0)

__device__ __forceinline__ void gload16(const void* g, void* l) {
  __builtin_amdgcn_global_load_lds((const __attribute__((address_space(1))) void*)g,
                                   (__attribute__((address_space(3))) void*)l,
                                   16, 0, 0);
}

// packed f32x2 -> bf16x2 (no builtin on gfx950; guide T12)
__device__ __forceinline__ uint32_t cvtpk(float lo, float hi) {
  uint32_t d;
  asm("v_cvt_pk_bf16_f32 %0, %1, %2" : "=v"(d) : "v"(lo), "v"(hi));
  return d;
}
// v_permlane32_swap_b32: a[32:63] <-> b[0:31].  s_nop guards the
// VALU-write -> permlane cross-lane-read hazard across asm blocks.
// a and b MUST be distinct SSA values (equal values coalesce to one VGPR
// and the swap self-cancels — round-2 bug).
__device__ __forceinline__ void pswap(uint32_t& a, uint32_t& b) {
  asm("s_nop 1\n\tv_permlane32_swap_b32 %0, %1" : "+v"(a), "+v"(b));
}
// raw v_exp_f32 (= 2^x).  exp2f() goes through OCML's denormal-guarded
// path (~5 ops, the round-4 VALU regression); this is 1 op.  Trailing
// s_nop 0 covers the TRANS->VALU wait state for the outside consumer.
__device__ __forceinline__ float fast_exp2(float x) {
  float r;
  asm("v_exp_f32 %0, %1\n\ts_nop 0" : "=v"(r) : "v"(x));
  return r;
}

// ---------------------------------------------------------------------------
// 1) prep: blocks [0,8192): x f32 -> xb bf16 (float4 each thread)
//          blocks [8192,10752): 64x64 LDS-tiled transpose of wq/wk/wv/wo
//          into bf16 [N][K] layouts.
// ---------------------------------------------------------------------------
__global__ void prep_kernel(const float* __restrict__ x, __bf16* __restrict__ xb,
                            const float* __restrict__ wq, const float* __restrict__ wk,
                            const float* __restrict__ wv, const float* __restrict__ wo,
                            __bf16* __restrict__ wqkvT, __bf16* __restrict__ woT) {
  __shared__ float tile[64][65];
  const int bid = blockIdx.x;
  const int tid = threadIdx.x;
  if (bid < 8192) {
    size_t i = (size_t)bid * 256 + tid;
    const float4* xv = (const float4*)x;
    float4 v = xv[i];
    bf16x4 o;
    o[0] = (__bf16)v.x; o[1] = (__bf16)v.y; o[2] = (__bf16)v.z; o[3] = (__bf16)v.w;
    *(bf16x4*)(xb + i * 4) = o;
    return;
  }
  int b2 = bid - 8192;
  const float* W; __bf16* WT; int ldw, kx, ny;
  if (b2 < 1024)      { W = wq; WT = wqkvT;                        ldw = 2048; kx = b2 & 31; ny = b2 >> 5; }
  else if (b2 < 1280) { int t = b2 - 1024; W = wk; WT = wqkvT + (size_t)2048 * 2048; ldw = 512; kx = t & 31; ny = t >> 5; }
  else if (b2 < 1536) { int t = b2 - 1280; W = wv; WT = wqkvT + (size_t)2560 * 2048; ldw = 512; kx = t & 31; ny = t >> 5; }
  else                { int t = b2 - 1536; W = wo; WT = woT;       ldw = 2048; kx = t & 31; ny = t >> 5; }
  const int k0 = kx * 64, n0 = ny * 64;
#pragma unroll
  for (int r = 0; r < 16; ++r) {
    int idx = r * 256 + tid;
    int kr = idx >> 6, nc = idx & 63;
    tile[kr][nc] = W[(size_t)(k0 + kr) * ldw + n0 + nc];
  }
  __syncthreads();
#pragma unroll
  for (int r = 0; r < 16; ++r) {
    int idx = r * 256 + tid;
    int nr = idx >> 6, kc = idx & 63;
    WT[(size_t)(n0 + nr) * 2048 + k0 + kc] = (__bf16)tile[kc][nr];
  }
}

// ---------------------------------------------------------------------------
// 2/5) bf16 GEMM: C[M][N] = A[M][K] * Bt[N][K]^T.  128x128 tile, BK=64,
// 4 waves (2x2), 4x4 16x16x32 frags/wave.  global_load_lds(16B) staging with
// XOR swizzle applied on the *source* address (LDS dest linear) and on reads.
// DO_ROPE: fused RoPE epilogue on Q cols [0,2048) (also scaled by
// log2(e)/sqrt(HD), for the exp2-domain softmax) and K cols [2048,2560).
// Pair (2j,2j+1) lives in lane^1 (C-frag col = lane&15) -> one shfl_xor.
// ---------------------------------------------------------------------------
template <int OUT_F32, int DO_ROPE>
__global__ __launch_bounds__(256, 2) void gemm_kernel(
    const __bf16* __restrict__ A, int lda,
    const __bf16* __restrict__ Bt, int ldb,
    void* __restrict__ Cout, int ldc, int Kdim,
    const float* __restrict__ fc, const float* __restrict__ fs) {
  __shared__ __attribute__((aligned(16))) __bf16 As[128 * 64];
  __shared__ __attribute__((aligned(16))) __bf16 Bs[128 * 64];
  const int tid = threadIdx.x;
  const int w = tid >> 6, l = tid & 63, lg = l >> 4, lr = l & 15;
  const int wm = w >> 1, wn = w & 1;
  const int m0 = blockIdx.y * 128, n0 = blockIdx.x * 128;

  f32x4 acc[4][4] = {};

  for (int k0 = 0; k0 < Kdim; k0 += 64) {
#pragma unroll
    for (int t = 0; t < 4; ++t) {
      int o = (t * 256 + tid) * 16;       // linear byte offset in 16KB tile
      int row = o >> 7;                   // 128B rows (64 bf16)
      int slot = (o >> 4) & 7;
      int sw = slot ^ (row & 7);          // involution: pre-swizzled source
      gload16(A + (size_t)(m0 + row) * lda + k0 + sw * 8,
              (char*)As + t * 4096 + (w << 10));
      gload16(Bt + (size_t)(n0 + row) * ldb + k0 + sw * 8,
              (char*)Bs + t * 4096 + (w << 10));
    }
    __syncthreads();
#pragma unroll
    for (int c = 0; c < 2; ++c) {
      bf16x8 af[4];
#pragma unroll
      for (int mi = 0; mi < 4; ++mi) {
        int row = wm * 64 + mi * 16 + lr;
        int slot = (c * 4 + lg) ^ (row & 7);
        af[mi] = *(const bf16x8*)((const char*)As + row * 128 + slot * 16);
      }
#pragma unroll
      for (int ni = 0; ni < 4; ++ni) {
        int rn = wn * 64 + ni * 16 + lr;
        int slot = (c * 4 + lg) ^ (rn & 7);
        bf16x8 bfr = *(const bf16x8*)((const char*)Bs + rn * 128 + slot * 16);
#pragma unroll
        for (int mi = 0; mi < 4; ++mi)
          acc[mi][ni] = MFMA16(af[mi], bfr, acc[mi][ni]);
      }
    }
    __syncthreads();
  }

  if (DO_ROPE && n0 < 2560) {
    // RoPE epilogue (Q: scale by log2e/sqrt(128); K: no scale); V never here.
    const float qs = 0.12755102871936672f;   // log2(e)/sqrt(128)
#pragma unroll
    for (int mi = 0; mi < 4; ++mi)
#pragma unroll
      for (int ni = 0; ni < 4; ++ni)
#pragma unroll
        for (int i = 0; i < 4; ++i) {
          float v = acc[mi][ni][i];
          float p = __shfl_xor(v, 1);        // partner of the (xr,xi) pair
          int cc = n0 + wn * 64 + ni * 16 + lr;
          int r  = m0 + wm * 64 + mi * 16 + lg * 4 + i;
          int s  = r & (S_LEN - 1);
          int j  = (cc & 127) >> 1;
          float c = fc[s * 64 + j], sn = fs[s * 64 + j];
          float o = (lr & 1) ? (p * sn + v * c)    // odd col: xr*sin + xi*cos
                             : (v * c - p * sn);   // even col: xr*cos - xi*sin
          if (cc < DMODEL) o *= qs;
          ((__bf16*)Cout)[(size_t)r * ldc + cc] = (__bf16)o;
        }
    return;
  }

#pragma unroll
  for (int mi = 0; mi < 4; ++mi)
#pragma unroll
    for (int ni = 0; ni < 4; ++ni)
#pragma unroll
      for (int i = 0; i < 4; ++i) {
        int r = m0 + wm * 64 + mi * 16 + lg * 4 + i;
        int cc = n0 + wn * 64 + ni * 16 + lr;
        if (OUT_F32)
          ((float*)Cout)[(size_t)r * ldc + cc] = acc[mi][ni][i];
        else
          ((__bf16*)Cout)[(size_t)r * ldc + cc] = (__bf16)acc[mi][ni][i];
      }
}

// ---------------------------------------------------------------------------
// 3) V part of qkv (cols [2560,3072)) -> VT [b][kvh][d][s] bf16 (64x64 tiles)
// ---------------------------------------------------------------------------
__global__ void vt_kernel(const __bf16* __restrict__ qkv, __bf16* __restrict__ VT) {
  __shared__ uint16_t tile[64][66];
  const int bkv = blockIdx.z;            // b*4 + kvh
  const int b = bkv >> 2, kv = bkv & 3;
  const int s0 = blockIdx.x * 64, d0 = blockIdx.y * 64;
  const int tid = threadIdx.x;
#pragma unroll
  for (int r = 0; r < 16; ++r) {
    int idx = r * 256 + tid;
    int sr = idx >> 6, dc = idx & 63;
    tile[sr][dc] = *(const uint16_t*)(qkv + (size_t)(b * S_LEN + s0 + sr) * NQKV +
                                      (DMODEL + NKVH * HD_) + kv * HD_ + d0 + dc);
  }
  __syncthreads();
#pragma unroll
  for (int r = 0; r < 16; ++r) {
    int idx = r * 256 + tid;
    int dr = idx >> 6, sc = idx & 63;
    *(uint16_t*)(VT + (size_t)(bkv * HD_ + d0 + dr) * S_LEN + s0 + sc) = tile[sc][dr];
  }
}

// ---------------------------------------------------------------------------
// 4) Flash attention — swapped-operand 32x32 MFMA, exp2-domain softmax.
// Double-buffered K/V staging with STATIC buffers (Ks0/Ks1/Vs0/Vs1 as
// distinct __shared__ objects + manual 2x unroll -> compile-time LDS
// addresses, so alias analysis does NOT insert an early vmcnt(0) before the
// current tile's ds_reads; the only drain is the __syncthreads() that lands
// after the full compute phase — guide T3 minimum-2-phase).
// ---------------------------------------------------------------------------
__global__ __launch_bounds__(256, 2) void attn_kernel(
    const __bf16* __restrict__ qkv, const __bf16* __restrict__ VT,
    __bf16* __restrict__ out) {
  __shared__ __attribute__((aligned(16))) __bf16 Ks0[64 * 128];
  __shared__ __attribute__((aligned(16))) __bf16 Ks1[64 * 128];
  __shared__ __attribute__((aligned(16))) __bf16 Vs0[128 * 64];
  __shared__ __attribute__((aligned(16))) __bf16 Vs1[128 * 64];
  const int tid = threadIdx.x;
  const int w = tid >> 6, l = tid & 63;
  const int qc = l & 31, hi = l >> 5;
  const int bh = blockIdx.y;             // 0..31
  const int b = bh >> 4, h = bh & 15, kvh = h >> 2;
  const int q0 = blockIdx.x * 128 + w * 32;   // wave's first q row within S

  const __bf16* Kbase = qkv + (size_t)b * S_LEN * NQKV + DMODEL + kvh * HD_;
  const __bf16* Vbase = VT + (size_t)(b * NKVH + kvh) * (HD_ * S_LEN);

  // stage K tile [64][256B] and V^T tile [128][128B] for kv-tile kt
  auto stage = [&](int kt, __bf16* ksb, __bf16* vsb) {
#pragma unroll
    for (int t = 0; t < 4; ++t) {
      int o = (t * 256 + tid) * 16;
      {
        int row = o >> 8; int slot = (o >> 4) & 15; int sw = slot ^ (row & 7);
        gload16(Kbase + (size_t)(kt * 64 + row) * NQKV + sw * 8,
                (char*)ksb + t * 4096 + (w << 10));
      }
      {
        int row = o >> 7; int slot = (o >> 4) & 7; int sw = slot ^ (row & 7);
        gload16(Vbase + (size_t)row * S_LEN + kt * 64 + sw * 8,
                (char*)vsb + t * 4096 + (w << 10));
      }
    }
  };

  // Q fragments (B-operand): lane holds Q[q0+qc][k = c*16 + hi*8 + j]
  bf16x8 aq[8];
#pragma unroll
  for (int c = 0; c < 8; ++c)
    aq[c] = *(const bf16x8*)(qkv + (size_t)(b * S_LEN + q0 + qc) * NQKV +
                             h * HD_ + c * 16 + hi * 8);

  f32x16 o_acc[4] = {};                  // O^T: rows d = 32dt + crow(r,hi), col q
  float m = -1e30f, lsum = 0.0f;

  typedef union { uint32_t u[4]; bf16x8 v; } pfrag_t;

  // one kv-tile's compute (QK^T -> online softmax -> P-pack -> PV)
  auto tile_step = [&](const __bf16* ksb, const __bf16* vsb) {
    // ---- swapped QK^T: st[t] = S^T[kv = 32t + crow(r,hi)][q = qc] (log2-dom)
    f32x16 st[2] = {};
    __builtin_amdgcn_s_setprio(1);
#pragma unroll
    for (int t = 0; t < 2; ++t) {
#pragma unroll
      for (int c = 0; c < 8; ++c) {
        int row = t * 32 + qc;
        int slot = (c * 2 + hi) ^ (row & 7);
        bf16x8 kf = *(const bf16x8*)((const char*)ksb + row * 256 + slot * 16);
        st[t] = MFMA32(kf, aq[c], st[t]);
      }
    }
    __builtin_amdgcn_s_setprio(0);

    // ---- in-register softmax (lane owns one q row; pair lane = other half)
    float pm = st[0][0];
#pragma unroll
    for (int t = 0; t < 2; ++t)
#pragma unroll
      for (int r = 0; r < 16; ++r) pm = fmaxf(pm, st[t][r]);
    pm = fmaxf(pm, __shfl_xor(pm, 32));

    if (__any(pm - m > 11.54f)) {        // defer-max (T13), 8*log2(e)
      float mn = fmaxf(m, pm);
      float sf = fast_exp2(m - mn);
      lsum *= sf;
#pragma unroll
      for (int dt = 0; dt < 4; ++dt)
#pragma unroll
        for (int r = 0; r < 16; ++r) o_acc[dt][r] *= sf;
      m = mn;
    }

    float rsum = 0.0f;
#pragma unroll
    for (int t = 0; t < 2; ++t)
#pragma unroll
      for (int r = 0; r < 16; ++r) {
        st[t][r] = fast_exp2(st[t][r] - m);
        rsum += st[t][r];
      }
    rsum += __shfl_xor(rsum, 32);
    lsum += rsum;

    // ---- pack P -> bf16 PV fragments (cvt_pk + permlane32_swap, T12)
    pfrag_t pf[4];
#pragma unroll
    for (int t = 0; t < 2; ++t)
#pragma unroll
      for (int half = 0; half < 2; ++half) {
        int bs = half * 8;
        uint32_t x0 = cvtpk(st[t][bs + 0], st[t][bs + 1]);
        uint32_t y0 = cvtpk(st[t][bs + 4], st[t][bs + 5]);
        uint32_t x1 = cvtpk(st[t][bs + 2], st[t][bs + 3]);
        uint32_t y1 = cvtpk(st[t][bs + 6], st[t][bs + 7]);
        pswap(x0, y0);
        pswap(x1, y1);
        pf[t * 2 + half].u[0] = x0;
        pf[t * 2 + half].u[1] = x1;
        pf[t * 2 + half].u[2] = y0;
        pf[t * 2 + half].u[3] = y1;
      }

    // ---- PV transposed: O^T += mfma32(V^T_frag, P^T_frag)
    __builtin_amdgcn_s_setprio(1);
#pragma unroll
    for (int dt = 0; dt < 4; ++dt) {
#pragma unroll
      for (int ks = 0; ks < 4; ++ks) {
        int row = dt * 32 + qc;
        int slot = (ks * 2 + hi) ^ (row & 7);
        bf16x8 vf = *(const bf16x8*)((const char*)vsb + row * 128 + slot * 16);
        o_acc[dt] = MFMA32(vf, pf[ks].v, o_acc[dt]);
      }
    }
    __builtin_amdgcn_s_setprio(0);
  };

  stage(0, Ks0, Vs0);
  __syncthreads();

#pragma unroll 1
  for (int kt = 0; kt < S_LEN / 64; kt += 2) {
    stage(kt + 1, Ks1, Vs1);             // issue-early into the OTHER buffer
    tile_step(Ks0, Vs0);
    __syncthreads();                     // drain lands after full compute
    if (kt + 2 < S_LEN / 64) stage(kt + 2, Ks0, Vs0);
    tile_step(Ks1, Vs1);
    __syncthreads();
  }

  // ---- epilogue: normalize, write bf16 attn-out [b*S][H*HD]
  float rinv = 1.0f / lsum;
  const size_t orow = (size_t)(b * S_LEN + q0 + qc) * DMODEL + h * HD_;
#pragma unroll
  for (int dt = 0; dt < 4; ++dt)
#pragma unroll
    for (int rg = 0; rg < 4; ++rg) {
      bf16x4 ov;
#pragma unroll
      for (int i = 0; i < 4; ++i)
        ov[i] = (__bf16)(o_acc[dt][rg * 4 + i] * rinv);
      int d = dt * 32 + rg * 8 + hi * 4;   // crow(rg*4+i,hi) = i + 8rg + 4hi
      *(bf16x4*)(out + orow + d) = ov;
    }
}

// ---------------------------------------------------------------------------
extern "C" void kernel_launch(void* const* d_in, const int* in_sizes, int n_in,
                              void* d_out, int out_size, void* d_ws, size_t ws_size,
                              hipStream_t stream) {
  const float* x  = (const float*)d_in[0];
  const float* fc = (const float*)d_in[1];
  const float* fs = (const float*)d_in[2];
  const float* wq = (const float*)d_in[3];
  const float* wk = (const float*)d_in[4];
  const float* wv = (const float*)d_in[5];
  const float* wo = (const float*)d_in[6];
  // d_in[7]/d_in[8] caches unused (start_pos==0, s==S), d_in[9] start_pos==0.

  char* ws = (char*)d_ws;
  __bf16* xb    = (__bf16*)(ws);                         // 16 MiB (reused as attn-out)
  __bf16* wqkvT = (__bf16*)(ws + (16u << 20));           // 12 MiB: [3072][2048]
  __bf16* woT   = (__bf16*)(ws + (28u << 20));           //  8 MiB: [2048][2048]
  __bf16* qkv   = (__bf16*)(ws + (36u << 20));           // 24 MiB: [4096][3072]
  __bf16* VT    = (__bf16*)(ws + (60u << 20));           //  4 MiB: [2][4][128][2048]

  // 1) x->bf16 + all weight transposes (one launch)
  prep_kernel<<<10752, 256, 0, stream>>>(x, xb, wq, wk, wv, wo, wqkvT, woT);
  // 2) fused QKV projection + RoPE epilogue -> qkv bf16 [4096][3072]
  {
    dim3 g(NQKV / 128, MROWS / 128);
    gemm_kernel<0, 1><<<g, 256, 0, stream>>>(xb, 2048, wqkvT, 2048, qkv, NQKV, 2048, fc, fs);
  }
  // 3) V -> V^T
  {
    dim3 g(32, 2, 8); vt_kernel<<<g, 256, 0, stream>>>(qkv, VT);
  }
  // 4) flash attention -> xb (attn-out bf16 [4096][2048])
  {
    dim3 g(S_LEN / 128, 32); attn_kernel<<<g, 256, 0, stream>>>(qkv, VT, xb);
  }
  // 5) output projection -> d_out f32
  {
    dim3 g(DMODEL / 128, MROWS / 128);
    gemm_kernel<1, 0><<<g, 256, 0, stream>>>(xb, 2048, woT, 2048, d_out, 2048, 2048, fc, fs);
  }
}